// Round 13
// baseline (119.466 us; speedup 1.0000x reference)
//
#include <hip/hip_runtime.h>
#include <math.h>

#define N_ROWS 8192
#define D_DIM  256
#define C_CLS  100
#define BM 128
#define BK 64
#define NSTRIP (N_ROWS / BM)              // 64
#define NBLK (NSTRIP * (NSTRIP + 1) / 2)  // 2080
#define UPK (C_CLS * (C_CLS + 1) / 2)     // 5050 packed unordered class-pair bins
#define MAXSEG 4                          // class segments per 64-row window
#define NHB (N_ROWS / 256)                // 32 hist/scatter blocks

typedef __attribute__((ext_vector_type(8))) __bf16 bf16x8;
typedef __attribute__((ext_vector_type(4))) float  floatx4;

__device__ __forceinline__ unsigned short f2bf(float x) {
    unsigned int u = __float_as_uint(x);
    u += 0x7fff + ((u >> 16) & 1);        // RNE
    return (unsigned short)(u >> 16);
}

__device__ __forceinline__ void gl2lds16(const void* g, void* l) {
    __builtin_amdgcn_global_load_lds(
        (const __attribute__((address_space(1))) void*)g,
        (__attribute__((address_space(3))) void*)l, 16, 0, 0);
}

// ---- K0: per-block label histograms (parallel, no global atomics) ----------
__global__ void hist_k(const int* __restrict__ labels, int* __restrict__ hist_part) {
    __shared__ int h[C_CLS];
    const int t = threadIdx.x;
    if (t < C_CLS) h[t] = 0;
    __syncthreads();
    atomicAdd(&h[labels[blockIdx.x * 256 + t]], 1);
    __syncthreads();
    if (t < C_CLS) hist_part[blockIdx.x * C_CLS + t] = h[t];
}

// ---- K1: class offsets + per-block class offsets + zero Ug -----------------
__global__ void scan_k(const int* __restrict__ hist_part, int* __restrict__ offs,
                       int* __restrict__ blockoffs, float* __restrict__ Ug) {
    __shared__ int tot[C_CLS];
    const int t = threadIdx.x;
    if (t < C_CLS) {
        int run = 0;
        for (int b = 0; b < NHB; ++b) {
            blockoffs[b * C_CLS + t] = run;          // intra-class prefix over blocks
            run += hist_part[b * C_CLS + t];
        }
        tot[t] = run;
    }
    __syncthreads();
    if (t == 0) {
        int run = 0;
        for (int c = 0; c < C_CLS; ++c) { offs[c] = run; run += tot[c]; }
        offs[C_CLS] = run;
    }
    for (int e = t; e < UPK; e += 256) Ug[e] = 0.f;
}

// ---- K2: contention-free deterministic counting-sort scatter ---------------
__global__ void scatter_k(const int* __restrict__ labels, const int* __restrict__ offs,
                          const int* __restrict__ blockoffs, int* __restrict__ dest,
                          int* __restrict__ slab) {
    __shared__ int cur[C_CLS];
    const int t = threadIdx.x;
    if (t < C_CLS) cur[t] = offs[t] + blockoffs[blockIdx.x * C_CLS + t];
    __syncthreads();
    const int i  = blockIdx.x * 256 + t;
    const int la = labels[i];
    const int pos = atomicAdd(&cur[la], 1);          // rank within this block's class run
    dest[i] = pos;
    slab[pos] = la;
}

// ---- K3: L2-normalize rows -> bf16 at sorted slot. One wave per row. -------
__global__ void normalize_k(const float* __restrict__ in, const int* __restrict__ dest,
                            unsigned short* __restrict__ fnb) {
    const int row  = blockIdx.x * 4 + (threadIdx.x >> 6);
    const int lane = threadIdx.x & 63;
    float4 v = ((const float4*)in)[row * 64 + lane];
    float s = v.x * v.x + v.y * v.y + v.z * v.z + v.w * v.w;
#pragma unroll
    for (int o = 32; o > 0; o >>= 1) s += __shfl_xor(s, o, 64);
    const float inv = 1.f / fmaxf(sqrtf(s), 1e-12f);
    const int d = dest[row];
    ushort4 o4;
    o4.x = f2bf(v.x * inv); o4.y = f2bf(v.y * inv);
    o4.z = f2bf(v.z * inv); o4.w = f2bf(v.w * inv);
    ((ushort4*)fnb)[d * 64 + lane] = o4;
}

// ---- K4: MFMA Gram (single-buffer BK=64 staging: 8 barrier events total) ---
// Tile-pair (ti <= tj). Off-diag: each unordered sample pair once -> weight 2.
// Diag: both orders -> weight 1; As == Bs so Bs staging is skipped and B-frags
// read from As. Registers bind occupancy to 4 blocks/CU (64 VGPR + 64 AGPR,
// R11); launch_bounds floor 4 (R10 spill cliff); NO __threadfence (R8).
__global__ __launch_bounds__(256, 4)
void main_k(const unsigned short* __restrict__ fnb, const int* __restrict__ slab,
            const int* __restrict__ offs_g, float* __restrict__ Ug) {
    __shared__ __align__(16) unsigned short As[BM * BK];   // 16 KB
    __shared__ __align__(16) unsigned short Bs[BM * BK];   // 16 KB
    __shared__ float red[4][MAXSEG * MAXSEG][17];   // [wave][combo][quad-sum]
    __shared__ int soffs[C_CLS + 1];
    __shared__ int meta[4][4];                      // per wave: cA0, cB0, segsA, segsB

    const int t = threadIdx.x;

    int b = blockIdx.x, ti = 0, len = NSTRIP;
    while (b >= len) { b -= len; ++ti; --len; }
    const int tj = ti + b;
    const int i0 = ti * BM, j0 = tj * BM;
    const bool diag = (ti == tj);

    if (t < C_CLS + 1) soffs[t] = offs_g[t];

    const int lane = t & 63;
    const int w    = t >> 6;
    const int m0 = (w & 1) * 64, n0 = (w >> 1) * 64;
    const int lr = lane & 15, lq = lane >> 4;
    const int swz = (lr >> 1) & 7;                  // row-swizzle over 8 chunks

    // frag row bases (ushort units; row stride BK=64) + physical chunk offsets
    int abase[4], bbase[4];
#pragma unroll
    for (int mb = 0; mb < 4; ++mb) abase[mb] = (m0 + mb * 16 + lr) * BK;
#pragma unroll
    for (int nb = 0; nb < 4; ++nb) bbase[nb] = (n0 + nb * 16 + lr) * BK;
    const int c0 = (lq ^ swz) * 8;                  // half 0 (k 0..31)
    const int c1 = ((lq ^ swz) ^ 4) * 8;            // half 1 (k 32..63)
    const unsigned short* Bsrc = diag ? As : Bs;    // diag: As == Bs content

    // staging: 8 slots/thread: s = t + 256*u; row = s>>3, physical chunk = s&7,
    // global chunk kc = (s&7) ^ ((row>>1)&7). LDS dst stays uniform+lane*16.
    int srow[4], skc[4];
#pragma unroll
    for (int u = 0; u < 4; ++u) {
        const int s = t + 256 * u;
        srow[u] = s >> 3;
        skc[u]  = (s & 7) ^ ((srow[u] >> 1) & 7);
    }

    floatx4 acc[4][4];
#pragma unroll
    for (int mb = 0; mb < 4; ++mb)
#pragma unroll
        for (int nb = 0; nb < 4; ++nb) acc[mb][nb] = 0.f;

#pragma unroll
    for (int k0 = 0; k0 < D_DIM; k0 += BK) {
        __syncthreads();                  // anti-dep: prev iter's frag reads done
#pragma unroll
        for (int u = 0; u < 4; ++u)
            gl2lds16(&fnb[(size_t)(i0 + srow[u]) * D_DIM + k0 + skc[u] * 8],
                     &As[(t + 256 * u) * 8]);
        if (!diag) {
#pragma unroll
            for (int u = 0; u < 4; ++u)
                gl2lds16(&fnb[(size_t)(j0 + srow[u]) * D_DIM + k0 + skc[u] * 8],
                         &Bs[(t + 256 * u) * 8]);
        }
        __syncthreads();                  // drain the loads just issued

#pragma unroll
        for (int h = 0; h < 2; ++h) {
            const int c = h ? c1 : c0;
            bf16x8 a[4], bb[4];
#pragma unroll
            for (int mb = 0; mb < 4; ++mb) a[mb]  = *(const bf16x8*)&As[abase[mb] + c];
#pragma unroll
            for (int nb = 0; nb < 4; ++nb) bb[nb] = *(const bf16x8*)&Bsrc[bbase[nb] + c];
#pragma unroll
            for (int mb = 0; mb < 4; ++mb)
#pragma unroll
                for (int nb = 0; nb < 4; ++nb)
                    acc[mb][nb] = __builtin_amdgcn_mfma_f32_16x16x32_bf16(a[mb], bb[nb], acc[mb][nb], 0, 0, 0);
        }
    }

    // ---- Gram -> dist in place (C/D: col=lane&15, row=lq*4+reg) ----
#pragma unroll
    for (int mb = 0; mb < 4; ++mb)
#pragma unroll
        for (int nb = 0; nb < 4; ++nb)
#pragma unroll
            for (int r = 0; r < 4; ++r) {
                const float g = acc[mb][nb][r];
                float dv = __builtin_amdgcn_sqrtf(fmaxf(2.f - 2.f * g, 0.f));
                const int rt = m0 + mb * 16 + lq * 4 + r;
                const int ct = n0 + nb * 16 + lr;
                if (diag && rt == ct) dv = 0.f;       // exact self-pair zero
                acc[mb][nb][r] = dv;
            }

    // wave-uniform class ranges from sorted labels
    const int cA0 = __builtin_amdgcn_readfirstlane(slab[i0 + m0]);
    const int cA1 = __builtin_amdgcn_readfirstlane(slab[i0 + m0 + 63]);
    const int cB0 = __builtin_amdgcn_readfirstlane(slab[j0 + n0]);
    const int cB1 = __builtin_amdgcn_readfirstlane(slab[j0 + n0 + 63]);
    const int segsA = cA1 - cA0 + 1, segsB = cB1 - cB0 + 1;
    if (lane == 0) { meta[w][0] = cA0; meta[w][1] = cB0; meta[w][2] = segsA; meta[w][3] = segsB; }
    const float wscale = diag ? 1.f : 2.f;

    // row totals -> rem; per-cb colsum via subtraction telescope
    float rem[4][4];
#pragma unroll
    for (int mb = 0; mb < 4; ++mb)
#pragma unroll
        for (int r = 0; r < 4; ++r)
            rem[mb][r] = acc[mb][0][r] + acc[mb][1][r] + acc[mb][2][r] + acc[mb][3][r];

    for (int sb = 0; sb < segsB; ++sb) {
        const int cb = cB0 + sb;
        float colsum[4][4];
        if (sb == segsB - 1) {
#pragma unroll
            for (int mb = 0; mb < 4; ++mb)
#pragma unroll
                for (int r = 0; r < 4; ++r) colsum[mb][r] = rem[mb][r];
        } else {
            const int rb0 = max(soffs[cb]     - j0, n0);
            const int rb1 = min(soffs[cb + 1] - j0, n0 + 64);
#pragma unroll
            for (int mb = 0; mb < 4; ++mb)
#pragma unroll
                for (int r = 0; r < 4; ++r) colsum[mb][r] = 0.f;
#pragma unroll
            for (int nb = 0; nb < 4; ++nb) {
                const int ct = n0 + nb * 16 + lr;
                const float mk = ((ct >= rb0) & (ct < rb1)) ? 1.f : 0.f;  // 1 cndmask
#pragma unroll
                for (int mb = 0; mb < 4; ++mb)
#pragma unroll
                    for (int r = 0; r < 4; ++r)
                        colsum[mb][r] = fmaf(mk, acc[mb][nb][r], colsum[mb][r]);  // fmac
            }
#pragma unroll
            for (int mb = 0; mb < 4; ++mb)
#pragma unroll
                for (int r = 0; r < 4; ++r) rem[mb][r] -= colsum[mb][r];
        }
        for (int sa = 0; sa < segsA; ++sa) {
            const int ca = cA0 + sa;
            const int ra0 = max(soffs[ca]     - i0, m0);
            const int ra1 = min(soffs[ca + 1] - i0, m0 + 64);
            float v = 0.f;
#pragma unroll
            for (int mb = 0; mb < 4; ++mb) {
                const int rtb = m0 + mb * 16 + lq * 4;
#pragma unroll
                for (int r = 0; r < 4; ++r) {
                    const int rt = rtb + r;
                    const bool ir = (rt >= ra0) & (rt < ra1);
                    v += ir ? colsum[mb][r] : 0.f;
                }
            }
            if (sa < MAXSEG && sb < MAXSEG) {
                v += __shfl_xor(v, 1, 64);            // quad pre-reduce (independent pairs)
                v += __shfl_xor(v, 2, 64);
                if ((lane & 3) == 0) red[w][sb * MAXSEG + sa][lane >> 2] = v;
            } else {                                  // overflow fallback (not hit for this data)
#pragma unroll
                for (int o = 32; o > 0; o >>= 1) v += __shfl_xor(v, o, 64);
                if (lane == 0 && v != 0.f) {
                    const int mn = min(ca, cb), mx = max(ca, cb);
                    atomicAdd(&Ug[mx + ((mn * (2 * C_CLS - 1 - mn)) >> 1)], wscale * v);
                }
            }
        }
    }

    __syncthreads();
    // cooperative reduce: 64 combos x 16 quad-sums; 4 threads per combo
    {
        const int combo = t >> 2, q = t & 3;
        const int wv = combo >> 4, sl = combo & 15;
        float s = red[wv][sl][q * 4 + 0] + red[wv][sl][q * 4 + 1]
                + red[wv][sl][q * 4 + 2] + red[wv][sl][q * 4 + 3];
        s += __shfl_xor(s, 1, 64);
        s += __shfl_xor(s, 2, 64);
        const int sa = sl & (MAXSEG - 1), sb = sl >> 2;
        if (q == 0 && sa < meta[wv][2] && sb < meta[wv][3] && s != 0.f) {
            const int ca = meta[wv][0] + sa, cb = meta[wv][1] + sb;
            const int mn = min(ca, cb), mx = max(ca, cb);
            atomicAdd(&Ug[mx + ((mn * (2 * C_CLS - 1 - mn)) >> 1)], wscale * s);
        }
    }
}

// ---- K5: finalize (counts from offs; no label pass) ------------------------
__global__ void finalize_k(const float* __restrict__ U, const int* __restrict__ offs,
                           float* __restrict__ out) {
    __shared__ int   cnt[C_CLS];
    __shared__ float rf[256];
    __shared__ int   ri[256];
    const int t = threadIdx.x;
    if (t < C_CLS) cnt[t] = offs[t + 1] - offs[t];
    __syncthreads();

    float s_intra = 0.f; int n_intra = 0;
    if (t < C_CLS) {
        int c = cnt[t];
        if (c > 1) {
            int idx = t + ((t * (2 * C_CLS - 1 - t)) >> 1);
            s_intra = U[idx] / ((float)c * (float)(c - 1));
            n_intra = 1;
        }
    }
    float s_inter = 0.f; int n_pairs = 0;
    for (int p = t; p < C_CLS * C_CLS; p += 256) {
        int a = p / C_CLS, b2 = p - a * C_CLS;
        if (b2 > a && cnt[a] > 0 && cnt[b2] > 0) {
            int idx = b2 + ((a * (2 * C_CLS - 1 - a)) >> 1);
            s_inter += 0.5f * U[idx] / ((float)cnt[a] * (float)cnt[b2]);
            ++n_pairs;
        }
    }

    rf[t] = s_intra; ri[t] = n_intra; __syncthreads();
    for (int s = 128; s > 0; s >>= 1) {
        if (t < s) { rf[t] += rf[t + s]; ri[t] += ri[t + s]; }
        __syncthreads();
    }
    float intra_sum = rf[0]; int intra_n = ri[0];
    __syncthreads();
    rf[t] = s_inter; ri[t] = n_pairs; __syncthreads();
    for (int s = 128; s > 0; s >>= 1) {
        if (t < s) { rf[t] += rf[t + s]; ri[t] += ri[t + s]; }
        __syncthreads();
    }
    if (t == 0) {
        float inter_sum = rf[0]; int pairs_n = ri[0];
        float intra = (intra_n > 0) ? intra_sum / (float)intra_n : 0.f;
        float inter = (pairs_n > 0) ? inter_sum / (float)pairs_n : 1.f;
        out[0] = fmaxf(intra - inter + 1.0f, 0.f);   // MARGIN = 1.0
    }
}

// ---- launch ----------------------------------------------------------------
extern "C" void kernel_launch(void* const* d_in, const int* in_sizes, int n_in,
                              void* d_out, int out_size, void* d_ws, size_t ws_size,
                              hipStream_t stream) {
    const float* feats  = (const float*)d_in[0];
    const int*   labels = (const int*)d_in[1];
    float* out = (float*)d_out;

    char* p = (char*)d_ws;
    unsigned short* fnb = (unsigned short*)p;  p += (size_t)N_ROWS * D_DIM * sizeof(unsigned short);
    int*   slab      = (int*)p;  p += (size_t)N_ROWS * sizeof(int);
    int*   dest      = (int*)p;  p += (size_t)N_ROWS * sizeof(int);
    int*   hist_part = (int*)p;  p += (size_t)NHB * C_CLS * sizeof(int);
    int*   blockoffs = (int*)p;  p += (size_t)NHB * C_CLS * sizeof(int);
    int*   offs      = (int*)p;  p += 128 * sizeof(int);
    float* Ug        = (float*)p;

    hist_k    <<<NHB, 256, 0, stream>>>(labels, hist_part);
    scan_k    <<<1, 256, 0, stream>>>(hist_part, offs, blockoffs, Ug);
    scatter_k <<<NHB, 256, 0, stream>>>(labels, offs, blockoffs, dest, slab);
    normalize_k<<<N_ROWS / 4, 256, 0, stream>>>(feats, dest, fnb);
    main_k    <<<NBLK, 256, 0, stream>>>(fnb, slab, offs, Ug);
    finalize_k<<<1, 256, 0, stream>>>(Ug, offs, out);
}

// Round 14
// 111.580 us; speedup vs baseline: 1.0707x; 1.0707x over previous
//
#include <hip/hip_runtime.h>
#include <math.h>

#define N_ROWS 8192
#define D_DIM  256
#define C_CLS  100
#define BM 128
#define BK 64
#define NSTRIP (N_ROWS / BM)              // 64
#define NBLK (NSTRIP * (NSTRIP + 1) / 2)  // 2080
#define UPK (C_CLS * (C_CLS + 1) / 2)     // 5050 packed unordered class-pair bins
#define MAXSEG 4                          // class segments per 64-row window

typedef __attribute__((ext_vector_type(8))) __bf16 bf16x8;
typedef __attribute__((ext_vector_type(4))) float  floatx4;

__device__ __forceinline__ unsigned short f2bf(float x) {
    unsigned int u = __float_as_uint(x);
    u += 0x7fff + ((u >> 16) & 1);        // RNE
    return (unsigned short)(u >> 16);
}

__device__ __forceinline__ void gl2lds16(const void* g, void* l) {
    __builtin_amdgcn_global_load_lds(
        (const __attribute__((address_space(1))) void*)g,
        (__attribute__((address_space(3))) void*)l, 16, 0, 0);
}

// ---- K0: single-block counting sort: hist + scan + scatter + zero Ug -------
// Merged single launch beats hist/scan/scatter split (R13: +2 launches cost
// more than the parallelism gained).
__global__ void sort_k(const int* __restrict__ labels, int* __restrict__ dest,
                       int* __restrict__ slab, int* __restrict__ offs,
                       float* __restrict__ Ug) {
    __shared__ int h[C_CLS];
    __shared__ int oS[C_CLS + 1];
    __shared__ int cur[C_CLS];
    const int t = threadIdx.x;            // 1024 threads
    if (t < C_CLS) h[t] = 0;
    __syncthreads();
    int myl[8];
#pragma unroll
    for (int u = 0; u < 8; ++u) myl[u] = labels[t + u * 1024];
#pragma unroll
    for (int u = 0; u < 8; ++u) atomicAdd(&h[myl[u]], 1);
    __syncthreads();
    if (t == 0) {
        int run = 0;
        for (int c = 0; c < C_CLS; ++c) { oS[c] = run; run += h[c]; }
        oS[C_CLS] = run;
    }
    __syncthreads();
    if (t < C_CLS) cur[t] = oS[t];
    __syncthreads();
#pragma unroll
    for (int u = 0; u < 8; ++u) {
        const int i = t + u * 1024;
        const int pos = atomicAdd(&cur[myl[u]], 1);   // rank within class
        dest[i] = pos;
        slab[pos] = myl[u];
    }
    if (t < C_CLS + 1) offs[t] = oS[t];
    for (int e = t; e < UPK; e += 1024) Ug[e] = 0.f;
}

// ---- K1: L2-normalize rows -> bf16 at sorted slot. One wave per row. -------
__global__ void normalize_k(const float* __restrict__ in, const int* __restrict__ dest,
                            unsigned short* __restrict__ fnb) {
    const int row  = blockIdx.x * 4 + (threadIdx.x >> 6);
    const int lane = threadIdx.x & 63;
    float4 v = ((const float4*)in)[row * 64 + lane];
    float s = v.x * v.x + v.y * v.y + v.z * v.z + v.w * v.w;
#pragma unroll
    for (int o = 32; o > 0; o >>= 1) s += __shfl_xor(s, o, 64);
    const float inv = 1.f / fmaxf(sqrtf(s), 1e-12f);
    const int d = dest[row];
    ushort4 o4;
    o4.x = f2bf(v.x * inv); o4.y = f2bf(v.y * inv);
    o4.z = f2bf(v.z * inv); o4.w = f2bf(v.w * inv);
    ((ushort4*)fnb)[d * 64 + lane] = o4;
}

// ---- K2: MFMA Gram (single-buffer BK=64 staging: 8 barrier events total) ---
// Tile-pair (ti <= tj). Off-diag: each unordered sample pair once -> weight 2.
// Diag: both orders -> weight 1. U[a,a]=S[a][a]; U[a,b]=2*S[a][b].
// Registers bind occupancy to 4 blocks/CU (64 VGPR + 64 AGPR acc = 128/thd,
// R11 lesson); BK=64 keeps LDS 37KB so 4 blocks still fit, and halves the
// per-block barrier+drain events vs BK=32 (R12 win: 122 -> 113.6 us).
// NO __threadfence (R8: = L2 wb/inv). launch_bounds floor 4 (R10 spill cliff).
__global__ __launch_bounds__(256, 4)
void main_k(const unsigned short* __restrict__ fnb, const int* __restrict__ slab,
            const int* __restrict__ offs_g, float* __restrict__ Ug) {
    __shared__ __align__(16) unsigned short As[BM * BK];   // 16 KB
    __shared__ __align__(16) unsigned short Bs[BM * BK];   // 16 KB
    __shared__ float red[4][MAXSEG * MAXSEG][17];   // [wave][combo][quad-sum]
    __shared__ int soffs[C_CLS + 1];
    __shared__ int meta[4][4];                      // per wave: cA0, cB0, segsA, segsB

    const int t = threadIdx.x;

    int b = blockIdx.x, ti = 0, len = NSTRIP;
    while (b >= len) { b -= len; ++ti; --len; }
    const int tj = ti + b;
    const int i0 = ti * BM, j0 = tj * BM;

    if (t < C_CLS + 1) soffs[t] = offs_g[t];

    const int lane = t & 63;
    const int w    = t >> 6;
    const int m0 = (w & 1) * 64, n0 = (w >> 1) * 64;
    const int lr = lane & 15, lq = lane >> 4;
    const int swz = (lr >> 1) & 7;                  // row-swizzle over 8 chunks

    // frag row bases (ushort units; row stride BK=64) + physical chunk offsets
    int abase[4], bbase[4];
#pragma unroll
    for (int mb = 0; mb < 4; ++mb) abase[mb] = (m0 + mb * 16 + lr) * BK;
#pragma unroll
    for (int nb = 0; nb < 4; ++nb) bbase[nb] = (n0 + nb * 16 + lr) * BK;
    const int c0 = (lq ^ swz) * 8;                  // half 0 (k 0..31)
    const int c1 = ((lq ^ swz) ^ 4) * 8;            // half 1 (k 32..63)

    // staging: 8 slots/thread: s = t + 256*u; row = s>>3, physical chunk = s&7,
    // global chunk kc = (s&7) ^ ((row>>1)&7). LDS dst stays uniform+lane*16.
    int srow[4], skc[4];
#pragma unroll
    for (int u = 0; u < 4; ++u) {
        const int s = t + 256 * u;
        srow[u] = s >> 3;
        skc[u]  = (s & 7) ^ ((srow[u] >> 1) & 7);
    }

    floatx4 acc[4][4];
#pragma unroll
    for (int mb = 0; mb < 4; ++mb)
#pragma unroll
        for (int nb = 0; nb < 4; ++nb) acc[mb][nb] = 0.f;

#pragma unroll
    for (int k0 = 0; k0 < D_DIM; k0 += BK) {
        __syncthreads();                  // anti-dep: prev iter's frag reads done
#pragma unroll
        for (int u = 0; u < 4; ++u)
            gl2lds16(&fnb[(size_t)(i0 + srow[u]) * D_DIM + k0 + skc[u] * 8],
                     &As[(t + 256 * u) * 8]);
#pragma unroll
        for (int u = 0; u < 4; ++u)
            gl2lds16(&fnb[(size_t)(j0 + srow[u]) * D_DIM + k0 + skc[u] * 8],
                     &Bs[(t + 256 * u) * 8]);
        __syncthreads();                  // drain the 8 loads just issued

#pragma unroll
        for (int h = 0; h < 2; ++h) {
            const int c = h ? c1 : c0;
            bf16x8 a[4], bb[4];
#pragma unroll
            for (int mb = 0; mb < 4; ++mb) a[mb]  = *(const bf16x8*)&As[abase[mb] + c];
#pragma unroll
            for (int nb = 0; nb < 4; ++nb) bb[nb] = *(const bf16x8*)&Bs[bbase[nb] + c];
#pragma unroll
            for (int mb = 0; mb < 4; ++mb)
#pragma unroll
                for (int nb = 0; nb < 4; ++nb)
                    acc[mb][nb] = __builtin_amdgcn_mfma_f32_16x16x32_bf16(a[mb], bb[nb], acc[mb][nb], 0, 0, 0);
        }
    }

    // ---- Gram -> dist in place (C/D: col=lane&15, row=lq*4+reg) ----
    const bool diag = (ti == tj);
#pragma unroll
    for (int mb = 0; mb < 4; ++mb)
#pragma unroll
        for (int nb = 0; nb < 4; ++nb)
#pragma unroll
            for (int r = 0; r < 4; ++r) {
                const float g = acc[mb][nb][r];
                float dv = __builtin_amdgcn_sqrtf(fmaxf(2.f - 2.f * g, 0.f));
                const int rt = m0 + mb * 16 + lq * 4 + r;
                const int ct = n0 + nb * 16 + lr;
                if (diag && rt == ct) dv = 0.f;       // exact self-pair zero
                acc[mb][nb][r] = dv;
            }

    // wave-uniform class ranges from sorted labels
    const int cA0 = __builtin_amdgcn_readfirstlane(slab[i0 + m0]);
    const int cA1 = __builtin_amdgcn_readfirstlane(slab[i0 + m0 + 63]);
    const int cB0 = __builtin_amdgcn_readfirstlane(slab[j0 + n0]);
    const int cB1 = __builtin_amdgcn_readfirstlane(slab[j0 + n0 + 63]);
    const int segsA = cA1 - cA0 + 1, segsB = cB1 - cB0 + 1;
    if (lane == 0) { meta[w][0] = cA0; meta[w][1] = cB0; meta[w][2] = segsA; meta[w][3] = segsB; }
    const float wscale = diag ? 1.f : 2.f;

    // row totals -> rem; per-cb colsum via subtraction telescope
    float rem[4][4];
#pragma unroll
    for (int mb = 0; mb < 4; ++mb)
#pragma unroll
        for (int r = 0; r < 4; ++r)
            rem[mb][r] = acc[mb][0][r] + acc[mb][1][r] + acc[mb][2][r] + acc[mb][3][r];

    for (int sb = 0; sb < segsB; ++sb) {
        const int cb = cB0 + sb;
        float colsum[4][4];
        if (sb == segsB - 1) {
#pragma unroll
            for (int mb = 0; mb < 4; ++mb)
#pragma unroll
                for (int r = 0; r < 4; ++r) colsum[mb][r] = rem[mb][r];
        } else {
            const int rb0 = max(soffs[cb]     - j0, n0);
            const int rb1 = min(soffs[cb + 1] - j0, n0 + 64);
#pragma unroll
            for (int mb = 0; mb < 4; ++mb)
#pragma unroll
                for (int r = 0; r < 4; ++r) colsum[mb][r] = 0.f;
#pragma unroll
            for (int nb = 0; nb < 4; ++nb) {
                const int ct = n0 + nb * 16 + lr;
                const float mk = ((ct >= rb0) & (ct < rb1)) ? 1.f : 0.f;  // 1 cndmask
#pragma unroll
                for (int mb = 0; mb < 4; ++mb)
#pragma unroll
                    for (int r = 0; r < 4; ++r)
                        colsum[mb][r] = fmaf(mk, acc[mb][nb][r], colsum[mb][r]);  // fmac
            }
#pragma unroll
            for (int mb = 0; mb < 4; ++mb)
#pragma unroll
                for (int r = 0; r < 4; ++r) rem[mb][r] -= colsum[mb][r];
        }
        for (int sa = 0; sa < segsA; ++sa) {
            const int ca = cA0 + sa;
            const int ra0 = max(soffs[ca]     - i0, m0);
            const int ra1 = min(soffs[ca + 1] - i0, m0 + 64);
            float v = 0.f;
#pragma unroll
            for (int mb = 0; mb < 4; ++mb) {
                const int rtb = m0 + mb * 16 + lq * 4;
#pragma unroll
                for (int r = 0; r < 4; ++r) {
                    const int rt = rtb + r;
                    const bool ir = (rt >= ra0) & (rt < ra1);
                    v += ir ? colsum[mb][r] : 0.f;
                }
            }
            if (sa < MAXSEG && sb < MAXSEG) {
                v += __shfl_xor(v, 1, 64);            // quad pre-reduce (independent pairs)
                v += __shfl_xor(v, 2, 64);
                if ((lane & 3) == 0) red[w][sb * MAXSEG + sa][lane >> 2] = v;
            } else {                                  // overflow fallback (not hit for this data)
#pragma unroll
                for (int o = 32; o > 0; o >>= 1) v += __shfl_xor(v, o, 64);
                if (lane == 0 && v != 0.f) {
                    const int mn = min(ca, cb), mx = max(ca, cb);
                    atomicAdd(&Ug[mx + ((mn * (2 * C_CLS - 1 - mn)) >> 1)], wscale * v);
                }
            }
        }
    }

    __syncthreads();
    // cooperative reduce: 64 combos x 16 quad-sums; 4 threads per combo
    {
        const int combo = t >> 2, q = t & 3;
        const int wv = combo >> 4, sl = combo & 15;
        float s = red[wv][sl][q * 4 + 0] + red[wv][sl][q * 4 + 1]
                + red[wv][sl][q * 4 + 2] + red[wv][sl][q * 4 + 3];
        s += __shfl_xor(s, 1, 64);
        s += __shfl_xor(s, 2, 64);
        const int sa = sl & (MAXSEG - 1), sb = sl >> 2;
        if (q == 0 && sa < meta[wv][2] && sb < meta[wv][3] && s != 0.f) {
            const int ca = meta[wv][0] + sa, cb = meta[wv][1] + sb;
            const int mn = min(ca, cb), mx = max(ca, cb);
            atomicAdd(&Ug[mx + ((mn * (2 * C_CLS - 1 - mn)) >> 1)], wscale * s);
        }
    }
}

// ---- K3: finalize (counts from offs; no label pass) ------------------------
__global__ void finalize_k(const float* __restrict__ U, const int* __restrict__ offs,
                           float* __restrict__ out) {
    __shared__ int   cnt[C_CLS];
    __shared__ float rf[256];
    __shared__ int   ri[256];
    const int t = threadIdx.x;
    if (t < C_CLS) cnt[t] = offs[t + 1] - offs[t];
    __syncthreads();

    float s_intra = 0.f; int n_intra = 0;
    if (t < C_CLS) {
        int c = cnt[t];
        if (c > 1) {
            int idx = t + ((t * (2 * C_CLS - 1 - t)) >> 1);
            s_intra = U[idx] / ((float)c * (float)(c - 1));
            n_intra = 1;
        }
    }
    float s_inter = 0.f; int n_pairs = 0;
    for (int p = t; p < C_CLS * C_CLS; p += 256) {
        int a = p / C_CLS, b2 = p - a * C_CLS;
        if (b2 > a && cnt[a] > 0 && cnt[b2] > 0) {
            int idx = b2 + ((a * (2 * C_CLS - 1 - a)) >> 1);
            s_inter += 0.5f * U[idx] / ((float)cnt[a] * (float)cnt[b2]);
            ++n_pairs;
        }
    }

    rf[t] = s_intra; ri[t] = n_intra; __syncthreads();
    for (int s = 128; s > 0; s >>= 1) {
        if (t < s) { rf[t] += rf[t + s]; ri[t] += ri[t + s]; }
        __syncthreads();
    }
    float intra_sum = rf[0]; int intra_n = ri[0];
    __syncthreads();
    rf[t] = s_inter; ri[t] = n_pairs; __syncthreads();
    for (int s = 128; s > 0; s >>= 1) {
        if (t < s) { rf[t] += rf[t + s]; ri[t] += ri[t + s]; }
        __syncthreads();
    }
    if (t == 0) {
        float inter_sum = rf[0]; int pairs_n = ri[0];
        float intra = (intra_n > 0) ? intra_sum / (float)intra_n : 0.f;
        float inter = (pairs_n > 0) ? inter_sum / (float)pairs_n : 1.f;
        out[0] = fmaxf(intra - inter + 1.0f, 0.f);   // MARGIN = 1.0
    }
}

// ---- launch ----------------------------------------------------------------
extern "C" void kernel_launch(void* const* d_in, const int* in_sizes, int n_in,
                              void* d_out, int out_size, void* d_ws, size_t ws_size,
                              hipStream_t stream) {
    const float* feats  = (const float*)d_in[0];
    const int*   labels = (const int*)d_in[1];
    float* out = (float*)d_out;

    char* p = (char*)d_ws;
    unsigned short* fnb = (unsigned short*)p;  p += (size_t)N_ROWS * D_DIM * sizeof(unsigned short);
    int*   slab = (int*)p;  p += (size_t)N_ROWS * sizeof(int);
    int*   dest = (int*)p;  p += (size_t)N_ROWS * sizeof(int);
    int*   offs = (int*)p;  p += 128 * sizeof(int);
    float* Ug   = (float*)p;

    sort_k     <<<1, 1024, 0, stream>>>(labels, dest, slab, offs, Ug);
    normalize_k<<<N_ROWS / 4, 256, 0, stream>>>(feats, dest, fnb);
    main_k     <<<NBLK, 256, 0, stream>>>(fnb, slab, offs, Ug);
    finalize_k <<<1, 256, 0, stream>>>(Ug, offs, out);
}

// Round 15
// 108.699 us; speedup vs baseline: 1.0991x; 1.0265x over previous
//
#include <hip/hip_runtime.h>
#include <math.h>

#define N_ROWS 8192
#define D_DIM  256
#define C_CLS  100
#define BM 128
#define BK 128                            // fp8: 128 k-cols per staging round
#define NSTRIP (N_ROWS / BM)              // 64
#define NBLK (NSTRIP * (NSTRIP + 1) / 2)  // 2080
#define UPK (C_CLS * (C_CLS + 1) / 2)     // 5050 packed unordered class-pair bins
#define MAXSEG 4                          // class segments per 64-row window

typedef __attribute__((ext_vector_type(4))) float floatx4;

__device__ __forceinline__ void gl2lds16(const void* g, void* l) {
    __builtin_amdgcn_global_load_lds(
        (const __attribute__((address_space(1))) void*)g,
        (__attribute__((address_space(3))) void*)l, 16, 0, 0);
}

// ---- K0: single-block counting sort: hist + scan + scatter + zero Ug -------
// Merged single launch beats hist/scan/scatter split (R13).
__global__ void sort_k(const int* __restrict__ labels, int* __restrict__ dest,
                       int* __restrict__ slab, int* __restrict__ offs,
                       float* __restrict__ Ug) {
    __shared__ int h[C_CLS];
    __shared__ int oS[C_CLS + 1];
    __shared__ int cur[C_CLS];
    const int t = threadIdx.x;            // 1024 threads
    if (t < C_CLS) h[t] = 0;
    __syncthreads();
    int myl[8];
#pragma unroll
    for (int u = 0; u < 8; ++u) myl[u] = labels[t + u * 1024];
#pragma unroll
    for (int u = 0; u < 8; ++u) atomicAdd(&h[myl[u]], 1);
    __syncthreads();
    if (t == 0) {
        int run = 0;
        for (int c = 0; c < C_CLS; ++c) { oS[c] = run; run += h[c]; }
        oS[C_CLS] = run;
    }
    __syncthreads();
    if (t < C_CLS) cur[t] = oS[t];
    __syncthreads();
#pragma unroll
    for (int u = 0; u < 8; ++u) {
        const int i = t + u * 1024;
        const int pos = atomicAdd(&cur[myl[u]], 1);   // rank within class
        dest[i] = pos;
        slab[pos] = myl[u];
    }
    if (t < C_CLS + 1) offs[t] = oS[t];
    for (int e = t; e < UPK; e += 1024) Ug[e] = 0.f;
}

// ---- K1: L2-normalize rows -> fp8 e4m3 at sorted slot. One wave per row. ---
// fp8 quant noise: ~1.5e-3/entry -> ~1.7e-3 in dot, zero-mean for i!=j pairs,
// averages to ~1e-5 in the class means (threshold 2e-2). Self-pairs zeroed
// explicitly in main_k.
__global__ void normalize_k(const float* __restrict__ in, const int* __restrict__ dest,
                            unsigned int* __restrict__ fnb8) {
    const int row  = blockIdx.x * 4 + (threadIdx.x >> 6);
    const int lane = threadIdx.x & 63;
    float4 v = ((const float4*)in)[row * 64 + lane];
    float s = v.x * v.x + v.y * v.y + v.z * v.z + v.w * v.w;
#pragma unroll
    for (int o = 32; o > 0; o >>= 1) s += __shfl_xor(s, o, 64);
    const float inv = 1.f / fmaxf(sqrtf(s), 1e-12f);
    const int d = dest[row];
    int pk = __builtin_amdgcn_cvt_pk_fp8_f32(v.x * inv, v.y * inv, 0, 0);   // bytes 0,1
    pk     = __builtin_amdgcn_cvt_pk_fp8_f32(v.z * inv, v.w * inv, pk, 1);  // bytes 2,3
    fnb8[d * 64 + lane] = (unsigned int)pk;           // 64 lanes x 4B = 256B row
}

// ---- K2: fp8 MFMA Gram (BK=128 single-buffer: only 2 barrier rounds) -------
// Tile-pair (ti <= tj). Off-diag: each unordered sample pair once -> weight 2.
// Diag: both orders -> weight 1. U[a,a]=S[a][a]; U[a,b]=2*S[a][b].
// fp8 halves staging bytes: whole 128-wide K-panel fits the same 16KB buffer
// -> 2 load+drain rounds vs 8 (R12). MFMA fp8 16x16x32 = bf16 rate (m11), so
// compute unchanged. Registers 64 VGPR + 64 AGPR -> 4 blocks/CU (R11);
// launch_bounds floor 4 (R10 spill cliff); NO __threadfence (R8).
__global__ __launch_bounds__(256, 4)
void main_k(const unsigned char* __restrict__ fnb8, const int* __restrict__ slab,
            const int* __restrict__ offs_g, float* __restrict__ Ug) {
    __shared__ __align__(16) unsigned char As[BM * BK];   // 16 KB
    __shared__ __align__(16) unsigned char Bs[BM * BK];   // 16 KB
    __shared__ float red[4][MAXSEG * MAXSEG][17];   // [wave][combo][quad-sum]
    __shared__ int soffs[C_CLS + 1];
    __shared__ int meta[4][4];                      // per wave: cA0, cB0, segsA, segsB

    const int t = threadIdx.x;

    int b = blockIdx.x, ti = 0, len = NSTRIP;
    while (b >= len) { b -= len; ++ti; --len; }
    const int tj = ti + b;
    const int i0 = ti * BM, j0 = tj * BM;

    if (t < C_CLS + 1) soffs[t] = offs_g[t];

    const int lane = t & 63;
    const int w    = t >> 6;
    const int m0 = (w & 1) * 64, n0 = (w >> 1) * 64;
    const int lr = lane & 15, lq = lane >> 4;
    const int swz = (lr >> 1) & 7;                  // row-swizzle over 8 chunks

    // frag row bases (byte units; row stride 128B = 8 chunks of 16B)
    int abase[4], bbase[4];
#pragma unroll
    for (int mb = 0; mb < 4; ++mb) abase[mb] = (m0 + mb * 16 + lr) * BK;
#pragma unroll
    for (int nb = 0; nb < 4; ++nb) bbase[nb] = (n0 + nb * 16 + lr) * BK;

    // staging: 4 slots/thread per buffer: s = t + 256*u; row = s>>3,
    // physical chunk = s&7, global chunk kc = (s&7) ^ ((row>>1)&7).
    // LDS dst = slot*16: wave-uniform base + lane*16 per issue.
    int srow[4], skc[4];
#pragma unroll
    for (int u = 0; u < 4; ++u) {
        const int s = t + 256 * u;
        srow[u] = s >> 3;
        skc[u]  = (s & 7) ^ ((srow[u] >> 1) & 7);
    }

    floatx4 acc[4][4];
#pragma unroll
    for (int mb = 0; mb < 4; ++mb)
#pragma unroll
        for (int nb = 0; nb < 4; ++nb) acc[mb][nb] = 0.f;

#pragma unroll
    for (int k0 = 0; k0 < D_DIM; k0 += BK) {
        __syncthreads();                  // anti-dep: prev round's frag reads done
#pragma unroll
        for (int u = 0; u < 4; ++u)
            gl2lds16(&fnb8[(size_t)(i0 + srow[u]) * D_DIM + k0 + skc[u] * 16],
                     &As[(t + 256 * u) * 16]);
#pragma unroll
        for (int u = 0; u < 4; ++u)
            gl2lds16(&fnb8[(size_t)(j0 + srow[u]) * D_DIM + k0 + skc[u] * 16],
                     &Bs[(t + 256 * u) * 16]);
        __syncthreads();                  // drain the 8 loads just issued

#pragma unroll
        for (int si = 0; si < 4; ++si) {  // 4 k-steps of 32 within the panel
            // lane's 8B frag: byte off = si*32 + lq*8 -> chunk si*2+(lq>>1), half lq&1
            const int coff = ((((si * 2) + (lq >> 1)) ^ swz) << 4) + ((lq & 1) << 3);
            long a[4], bb[4];
#pragma unroll
            for (int mb = 0; mb < 4; ++mb) a[mb]  = *(const long*)&As[abase[mb] + coff];
#pragma unroll
            for (int nb = 0; nb < 4; ++nb) bb[nb] = *(const long*)&Bs[bbase[nb] + coff];
#pragma unroll
            for (int mb = 0; mb < 4; ++mb)
#pragma unroll
                for (int nb = 0; nb < 4; ++nb)
                    acc[mb][nb] = __builtin_amdgcn_mfma_f32_16x16x32_fp8_fp8(
                        a[mb], bb[nb], acc[mb][nb], 0, 0, 0);
        }
    }

    // ---- Gram -> dist in place (C/D: col=lane&15, row=lq*4+reg) ----
    const bool diag = (ti == tj);
#pragma unroll
    for (int mb = 0; mb < 4; ++mb)
#pragma unroll
        for (int nb = 0; nb < 4; ++nb)
#pragma unroll
            for (int r = 0; r < 4; ++r) {
                const float g = acc[mb][nb][r];
                float dv = __builtin_amdgcn_sqrtf(fmaxf(2.f - 2.f * g, 0.f));
                const int rt = m0 + mb * 16 + lq * 4 + r;
                const int ct = n0 + nb * 16 + lr;
                if (diag && rt == ct) dv = 0.f;       // exact self-pair zero
                acc[mb][nb][r] = dv;
            }

    // wave-uniform class ranges from sorted labels
    const int cA0 = __builtin_amdgcn_readfirstlane(slab[i0 + m0]);
    const int cA1 = __builtin_amdgcn_readfirstlane(slab[i0 + m0 + 63]);
    const int cB0 = __builtin_amdgcn_readfirstlane(slab[j0 + n0]);
    const int cB1 = __builtin_amdgcn_readfirstlane(slab[j0 + n0 + 63]);
    const int segsA = cA1 - cA0 + 1, segsB = cB1 - cB0 + 1;
    if (lane == 0) { meta[w][0] = cA0; meta[w][1] = cB0; meta[w][2] = segsA; meta[w][3] = segsB; }
    const float wscale = diag ? 1.f : 2.f;

    // row totals -> rem; per-cb colsum via subtraction telescope
    float rem[4][4];
#pragma unroll
    for (int mb = 0; mb < 4; ++mb)
#pragma unroll
        for (int r = 0; r < 4; ++r)
            rem[mb][r] = acc[mb][0][r] + acc[mb][1][r] + acc[mb][2][r] + acc[mb][3][r];

    for (int sb = 0; sb < segsB; ++sb) {
        const int cb = cB0 + sb;
        float colsum[4][4];
        if (sb == segsB - 1) {
#pragma unroll
            for (int mb = 0; mb < 4; ++mb)
#pragma unroll
                for (int r = 0; r < 4; ++r) colsum[mb][r] = rem[mb][r];
        } else {
            const int rb0 = max(soffs[cb]     - j0, n0);
            const int rb1 = min(soffs[cb + 1] - j0, n0 + 64);
#pragma unroll
            for (int mb = 0; mb < 4; ++mb)
#pragma unroll
                for (int r = 0; r < 4; ++r) colsum[mb][r] = 0.f;
#pragma unroll
            for (int nb = 0; nb < 4; ++nb) {
                const int ct = n0 + nb * 16 + lr;
                const float mk = ((ct >= rb0) & (ct < rb1)) ? 1.f : 0.f;  // 1 cndmask
#pragma unroll
                for (int mb = 0; mb < 4; ++mb)
#pragma unroll
                    for (int r = 0; r < 4; ++r)
                        colsum[mb][r] = fmaf(mk, acc[mb][nb][r], colsum[mb][r]);  // fmac
            }
#pragma unroll
            for (int mb = 0; mb < 4; ++mb)
#pragma unroll
                for (int r = 0; r < 4; ++r) rem[mb][r] -= colsum[mb][r];
        }
        for (int sa = 0; sa < segsA; ++sa) {
            const int ca = cA0 + sa;
            const int ra0 = max(soffs[ca]     - i0, m0);
            const int ra1 = min(soffs[ca + 1] - i0, m0 + 64);
            float v = 0.f;
#pragma unroll
            for (int mb = 0; mb < 4; ++mb) {
                const int rtb = m0 + mb * 16 + lq * 4;
#pragma unroll
                for (int r = 0; r < 4; ++r) {
                    const int rt = rtb + r;
                    const bool ir = (rt >= ra0) & (rt < ra1);
                    v += ir ? colsum[mb][r] : 0.f;
                }
            }
            if (sa < MAXSEG && sb < MAXSEG) {
                v += __shfl_xor(v, 1, 64);            // quad pre-reduce (independent pairs)
                v += __shfl_xor(v, 2, 64);
                if ((lane & 3) == 0) red[w][sb * MAXSEG + sa][lane >> 2] = v;
            } else {                                  // overflow fallback (not hit for this data)
#pragma unroll
                for (int o = 32; o > 0; o >>= 1) v += __shfl_xor(v, o, 64);
                if (lane == 0 && v != 0.f) {
                    const int mn = min(ca, cb), mx = max(ca, cb);
                    atomicAdd(&Ug[mx + ((mn * (2 * C_CLS - 1 - mn)) >> 1)], wscale * v);
                }
            }
        }
    }

    __syncthreads();
    // cooperative reduce: 64 combos x 16 quad-sums; 4 threads per combo
    {
        const int combo = t >> 2, q = t & 3;
        const int wv = combo >> 4, sl = combo & 15;
        float s = red[wv][sl][q * 4 + 0] + red[wv][sl][q * 4 + 1]
                + red[wv][sl][q * 4 + 2] + red[wv][sl][q * 4 + 3];
        s += __shfl_xor(s, 1, 64);
        s += __shfl_xor(s, 2, 64);
        const int sa = sl & (MAXSEG - 1), sb = sl >> 2;
        if (q == 0 && sa < meta[wv][2] && sb < meta[wv][3] && s != 0.f) {
            const int ca = meta[wv][0] + sa, cb = meta[wv][1] + sb;
            const int mn = min(ca, cb), mx = max(ca, cb);
            atomicAdd(&Ug[mx + ((mn * (2 * C_CLS - 1 - mn)) >> 1)], wscale * s);
        }
    }
}

// ---- K3: finalize (counts from offs; no label pass) ------------------------
__global__ void finalize_k(const float* __restrict__ U, const int* __restrict__ offs,
                           float* __restrict__ out) {
    __shared__ int   cnt[C_CLS];
    __shared__ float rf[256];
    __shared__ int   ri[256];
    const int t = threadIdx.x;
    if (t < C_CLS) cnt[t] = offs[t + 1] - offs[t];
    __syncthreads();

    float s_intra = 0.f; int n_intra = 0;
    if (t < C_CLS) {
        int c = cnt[t];
        if (c > 1) {
            int idx = t + ((t * (2 * C_CLS - 1 - t)) >> 1);
            s_intra = U[idx] / ((float)c * (float)(c - 1));
            n_intra = 1;
        }
    }
    float s_inter = 0.f; int n_pairs = 0;
    for (int p = t; p < C_CLS * C_CLS; p += 256) {
        int a = p / C_CLS, b2 = p - a * C_CLS;
        if (b2 > a && cnt[a] > 0 && cnt[b2] > 0) {
            int idx = b2 + ((a * (2 * C_CLS - 1 - a)) >> 1);
            s_inter += 0.5f * U[idx] / ((float)cnt[a] * (float)cnt[b2]);
            ++n_pairs;
        }
    }

    rf[t] = s_intra; ri[t] = n_intra; __syncthreads();
    for (int s = 128; s > 0; s >>= 1) {
        if (t < s) { rf[t] += rf[t + s]; ri[t] += ri[t + s]; }
        __syncthreads();
    }
    float intra_sum = rf[0]; int intra_n = ri[0];
    __syncthreads();
    rf[t] = s_inter; ri[t] = n_pairs; __syncthreads();
    for (int s = 128; s > 0; s >>= 1) {
        if (t < s) { rf[t] += rf[t + s]; ri[t] += ri[t + s]; }
        __syncthreads();
    }
    if (t == 0) {
        float inter_sum = rf[0]; int pairs_n = ri[0];
        float intra = (intra_n > 0) ? intra_sum / (float)intra_n : 0.f;
        float inter = (pairs_n > 0) ? inter_sum / (float)pairs_n : 1.f;
        out[0] = fmaxf(intra - inter + 1.0f, 0.f);   // MARGIN = 1.0
    }
}

// ---- launch ----------------------------------------------------------------
extern "C" void kernel_launch(void* const* d_in, const int* in_sizes, int n_in,
                              void* d_out, int out_size, void* d_ws, size_t ws_size,
                              hipStream_t stream) {
    const float* feats  = (const float*)d_in[0];
    const int*   labels = (const int*)d_in[1];
    float* out = (float*)d_out;

    char* p = (char*)d_ws;
    unsigned char* fnb8 = (unsigned char*)p;  p += (size_t)N_ROWS * D_DIM;  // 2 MB fp8 rows
    int*   slab = (int*)p;  p += (size_t)N_ROWS * sizeof(int);
    int*   dest = (int*)p;  p += (size_t)N_ROWS * sizeof(int);
    int*   offs = (int*)p;  p += 128 * sizeof(int);
    float* Ug   = (float*)p;

    sort_k     <<<1, 1024, 0, stream>>>(labels, dest, slab, offs, Ug);
    normalize_k<<<N_ROWS / 4, 256, 0, stream>>>(feats, dest, (unsigned int*)fnb8);
    main_k     <<<NBLK, 256, 0, stream>>>(fnb8, slab, offs, Ug);
    finalize_k <<<1, 256, 0, stream>>>(Ug, offs, out);
}